// Round 1
// baseline (905.482 us; speedup 1.0000x reference)
//
#include <hip/hip_runtime.h>

#define NN 100000
#define NE 800000

static constexpr int NB1 = (NN + 1023) / 1024;  // scan pass-1 blocks = 98
static constexpr int NBT = (NN + 63) / 64;      // node-tile blocks = 1563

typedef __attribute__((ext_vector_type(8))) short short8;
typedef __attribute__((ext_vector_type(4))) float f32x4;

__device__ __forceinline__ unsigned short f2bf(float f) {
  unsigned int u = __float_as_uint(f);
  u += 0x7fffu + ((u >> 16) & 1u);
  return (unsigned short)(u >> 16);
}
__device__ __forceinline__ float bflo(unsigned int u) { return __uint_as_float(u << 16); }
__device__ __forceinline__ float bfhi(unsigned int u) { return __uint_as_float(u & 0xffff0000u); }

// ---------------- CSR build ----------------

__global__ void k_count(const int* __restrict__ ei, int* __restrict__ cnt) {
  int e = blockIdx.x * 256 + threadIdx.x;
  if (e < NE) atomicAdd(&cnt[ei[e]], 1);
}

// block=256, each thread 4 elems, chunk=1024/block
__global__ void k_scan1(const int* __restrict__ cnt, int* __restrict__ rp,
                        int* __restrict__ bsums) {
  __shared__ int sm[256];
  const int b = blockIdx.x, t = threadIdx.x;
  const int base = b * 1024 + t * 4;
  int c0 = 0, c1 = 0, c2 = 0, c3 = 0;
  if (base + 4 <= NN) {
    int4 v = *(const int4*)(cnt + base);
    c0 = v.x; c1 = v.y; c2 = v.z; c3 = v.w;
  } else {
    if (base + 0 < NN) c0 = cnt[base + 0];
    if (base + 1 < NN) c1 = cnt[base + 1];
    if (base + 2 < NN) c2 = cnt[base + 2];
    if (base + 3 < NN) c3 = cnt[base + 3];
  }
  int tot = c0 + c1 + c2 + c3;
  sm[t] = tot;
  __syncthreads();
  for (int off = 1; off < 256; off <<= 1) {
    int v = (t >= off) ? sm[t - off] : 0;
    __syncthreads();
    sm[t] += v;
    __syncthreads();
  }
  int incl = sm[t];
  int excl = incl - tot;
  if (t == 255) bsums[b] = incl;
  int run = excl;
  if (base + 0 < NN) rp[base + 0] = run; run += c0;
  if (base + 1 < NN) rp[base + 1] = run; run += c1;
  if (base + 2 < NN) rp[base + 2] = run; run += c2;
  if (base + 3 < NN) rp[base + 3] = run;
}

__global__ void k_scan2(int* __restrict__ bsums) {
  __shared__ int sm[128];
  int t = threadIdx.x;
  int v = (t < NB1) ? bsums[t] : 0;
  sm[t] = v;
  __syncthreads();
  for (int off = 1; off < 128; off <<= 1) {
    int u = (t >= off) ? sm[t - off] : 0;
    __syncthreads();
    sm[t] += u;
    __syncthreads();
  }
  if (t < NB1) bsums[t] = sm[t] - v;  // exclusive
}

__global__ void k_scan3(int* __restrict__ rp, int* __restrict__ cursor,
                        const int* __restrict__ bsums) {
  int i = blockIdx.x * 256 + threadIdx.x;
  if (i < NN) {
    int v = rp[i] + bsums[i >> 10];
    rp[i] = v;
    cursor[i] = v;
  }
  if (i == 0) rp[NN] = NE;
}

__global__ void k_fill(const int* __restrict__ ei, int* __restrict__ cursor,
                       int* __restrict__ col) {
  int e = blockIdx.x * 256 + threadIdx.x;
  if (e < NE) {
    int d = ei[e];
    int pos = atomicAdd(&cursor[d], 1);
    col[pos] = ei[NE + e];
  }
}

// ---------------- x -> bf16 ----------------

__global__ void k_cvt(const float* __restrict__ x, unsigned short* __restrict__ hb) {
  int i = blockIdx.x * 256 + threadIdx.x;
  long long base = (long long)i * 4;
  if (base < (long long)NN * 128) {
    float4 v = *(const float4*)(x + base);
    unsigned long long pk = (unsigned long long)f2bf(v.x) |
                            ((unsigned long long)f2bf(v.y) << 16) |
                            ((unsigned long long)f2bf(v.z) << 32) |
                            ((unsigned long long)f2bf(v.w) << 48);
    *(unsigned long long*)(hb + base) = pk;
  }
}

// ---------------- fused SAGE layer ----------------
// block = 256 threads (4 waves), 64 nodes per block (16 per wave).
// LDS: Wl+Wr bf16 in B-frag order (64KB) + per-wave agg A-frag staging (16KB) = 80KB
__global__ __launch_bounds__(256, 2)
void k_layer(const unsigned short* __restrict__ hin, unsigned short* __restrict__ hout,
             const int* __restrict__ rp, const int* __restrict__ col,
             const float* __restrict__ Wl, const float* __restrict__ bl,
             const float* __restrict__ Wr, const float* __restrict__ gmm,
             const float* __restrict__ bta) {
  __shared__ unsigned short Wfrag[32768];   // [mat(2)][c(4)][jt(8)][lane(64)][jj(8)]
  __shared__ unsigned short aggS[4][2048];  // per wave: [c(4)][lane(64)][jj(8)]
  const int t = threadIdx.x;
  const int w = t >> 6;
  const int lane = t & 63;
  const int nodeBase = blockIdx.x * 64;

  // stage W (f32 global -> bf16 LDS, fragment order)
  for (int idx = t; idx < 16384; idx += 256) {
    int j = idx >> 7, k = idx & 127;
    int c = k >> 5, q = (k >> 3) & 3, jj = k & 7, jt = j >> 4, j16 = j & 15;
    int slot = (c * 8 + jt) * 512 + (q * 16 + j16) * 8 + jj;
    Wfrag[slot] = f2bf(Wl[idx]);
    Wfrag[16384 + slot] = f2bf(Wr[idx]);
  }

  // gather: wave-per-node, lane = feature pair (2*lane, 2*lane+1)
  const unsigned int* hin32 = (const unsigned int*)hin;
  for (int m = 0; m < 16; ++m) {
    int n = nodeBase + w * 16 + m;
    float ax = 0.f, ay = 0.f;
    if (n < NN) {
      int e0 = rp[n], e1 = rp[n + 1];
      float inv = 1.f / fmaxf((float)(e1 - e0), 1.f);
      int e = e0;
      for (; e + 4 <= e1; e += 4) {
        int s0 = col[e], s1 = col[e + 1], s2 = col[e + 2], s3 = col[e + 3];
        unsigned int u0 = hin32[(size_t)s0 * 64 + lane];
        unsigned int u1 = hin32[(size_t)s1 * 64 + lane];
        unsigned int u2 = hin32[(size_t)s2 * 64 + lane];
        unsigned int u3 = hin32[(size_t)s3 * 64 + lane];
        ax += bflo(u0) + bflo(u1) + bflo(u2) + bflo(u3);
        ay += bfhi(u0) + bfhi(u1) + bfhi(u2) + bfhi(u3);
      }
      for (; e < e1; ++e) {
        unsigned int u = hin32[(size_t)col[e] * 64 + lane];
        ax += bflo(u);
        ay += bfhi(u);
      }
      ax *= inv;
      ay *= inv;
    }
    int k = lane * 2;
    int c = k >> 5, q = (k >> 3) & 3, jj = k & 7;
    unsigned int packed = ((unsigned int)f2bf(ay) << 16) | (unsigned int)f2bf(ax);
    *(unsigned int*)&aggS[w][c * 512 + (q * 16 + m) * 8 + jj] = packed;
  }
  __syncthreads();

  // MFMA: z[64 nodes][128 out] ; wave handles 16 nodes x 128 out
  f32x4 acc[8];
#pragma unroll
  for (int jt = 0; jt < 8; ++jt) acc[jt] = (f32x4){0.f, 0.f, 0.f, 0.f};
  const int q = lane >> 4;
  int nrow = nodeBase + w * 16 + (lane & 15);
  const unsigned short* hrow = hin + (size_t)(nrow < NN ? nrow : NN - 1) * 128;
#pragma unroll
  for (int c = 0; c < 4; ++c) {
    short8 a_agg = *(const short8*)&aggS[w][c * 512 + lane * 8];
    short8 a_h = *(const short8*)(hrow + c * 32 + q * 8);
#pragma unroll
    for (int jt = 0; jt < 8; ++jt) {
      short8 b_l = *(const short8*)&Wfrag[(c * 8 + jt) * 512 + lane * 8];
      short8 b_r = *(const short8*)&Wfrag[16384 + (c * 8 + jt) * 512 + lane * 8];
      acc[jt] = __builtin_amdgcn_mfma_f32_16x16x32_bf16(a_agg, b_l, acc[jt], 0, 0, 0);
      acc[jt] = __builtin_amdgcn_mfma_f32_16x16x32_bf16(a_h, b_r, acc[jt], 0, 0, 0);
    }
  }

  // epilogue: +bias, LayerNorm over 128 feats (xor-shuffle in 16-lane groups), ReLU
  const int n16 = lane & 15;
  float blv[8], gv[8], bv[8];
#pragma unroll
  for (int jt = 0; jt < 8; ++jt) {
    int j = jt * 16 + n16;
    blv[jt] = bl[j];
    gv[jt] = gmm[j];
    bv[jt] = bta[j];
  }
  float s[4] = {0, 0, 0, 0}, ss[4] = {0, 0, 0, 0};
#pragma unroll
  for (int jt = 0; jt < 8; ++jt)
#pragma unroll
    for (int r = 0; r < 4; ++r) {
      float v = acc[jt][r] + blv[jt];
      acc[jt][r] = v;
      s[r] += v;
      ss[r] += v * v;
    }
#pragma unroll
  for (int mask = 1; mask < 16; mask <<= 1) {
#pragma unroll
    for (int r = 0; r < 4; ++r) {
      s[r] += __shfl_xor(s[r], mask, 64);
      ss[r] += __shfl_xor(ss[r], mask, 64);
    }
  }
  float mu[4], rs[4];
#pragma unroll
  for (int r = 0; r < 4; ++r) {
    mu[r] = s[r] * (1.f / 128.f);
    float var = ss[r] * (1.f / 128.f) - mu[r] * mu[r];
    rs[r] = rsqrtf(var + 1e-5f);
  }
#pragma unroll
  for (int jt = 0; jt < 8; ++jt)
#pragma unroll
    for (int r = 0; r < 4; ++r) {
      int n = nodeBase + w * 16 + q * 4 + r;
      if (n < NN) {
        float v = (acc[jt][r] - mu[r]) * rs[r] * gv[jt] + bv[jt];
        hout[(size_t)n * 128 + jt * 16 + n16] = f2bf(fmaxf(v, 0.f));
      }
    }
}

// ---------------- final linear + log_softmax ----------------
__global__ __launch_bounds__(256, 2)
void k_final(const unsigned short* __restrict__ hin, const float* __restrict__ Wf,
             const float* __restrict__ bfp, float* __restrict__ out) {
  __shared__ unsigned short Wfrag[8192];  // [c(4)][jt(4)][lane(64)][jj(8)]
  const int t = threadIdx.x;
  const int w = t >> 6;
  const int lane = t & 63;
  const int nodeBase = blockIdx.x * 64;

  for (int idx = t; idx < 8192; idx += 256) {
    int j = idx >> 7, k = idx & 127;
    int c = k >> 5, q = (k >> 3) & 3, jj = k & 7, jt = j >> 4, j16 = j & 15;
    Wfrag[(c * 4 + jt) * 512 + (q * 16 + j16) * 8 + jj] = f2bf(Wf[idx]);
  }
  __syncthreads();

  f32x4 acc[4];
#pragma unroll
  for (int jt = 0; jt < 4; ++jt) acc[jt] = (f32x4){0.f, 0.f, 0.f, 0.f};
  const int q = lane >> 4;
  int nrow = nodeBase + w * 16 + (lane & 15);
  const unsigned short* hrow = hin + (size_t)(nrow < NN ? nrow : NN - 1) * 128;
#pragma unroll
  for (int c = 0; c < 4; ++c) {
    short8 a_h = *(const short8*)(hrow + c * 32 + q * 8);
#pragma unroll
    for (int jt = 0; jt < 4; ++jt) {
      short8 b = *(const short8*)&Wfrag[(c * 4 + jt) * 512 + lane * 8];
      acc[jt] = __builtin_amdgcn_mfma_f32_16x16x32_bf16(a_h, b, acc[jt], 0, 0, 0);
    }
  }

  const int n16 = lane & 15;
  float bfv[4];
#pragma unroll
  for (int jt = 0; jt < 4; ++jt) bfv[jt] = bfp[jt * 16 + n16];
  float mx[4] = {-1e30f, -1e30f, -1e30f, -1e30f};
#pragma unroll
  for (int jt = 0; jt < 4; ++jt)
#pragma unroll
    for (int r = 0; r < 4; ++r) {
      float v = acc[jt][r] + bfv[jt];
      acc[jt][r] = v;
      mx[r] = fmaxf(mx[r], v);
    }
#pragma unroll
  for (int mask = 1; mask < 16; mask <<= 1)
#pragma unroll
    for (int r = 0; r < 4; ++r) mx[r] = fmaxf(mx[r], __shfl_xor(mx[r], mask, 64));
  float se[4] = {0, 0, 0, 0};
#pragma unroll
  for (int jt = 0; jt < 4; ++jt)
#pragma unroll
    for (int r = 0; r < 4; ++r) se[r] += expf(acc[jt][r] - mx[r]);
#pragma unroll
  for (int mask = 1; mask < 16; mask <<= 1)
#pragma unroll
    for (int r = 0; r < 4; ++r) se[r] += __shfl_xor(se[r], mask, 64);
  float lse[4];
#pragma unroll
  for (int r = 0; r < 4; ++r) lse[r] = mx[r] + logf(se[r]);
#pragma unroll
  for (int jt = 0; jt < 4; ++jt)
#pragma unroll
    for (int r = 0; r < 4; ++r) {
      int n = nodeBase + w * 16 + q * 4 + r;
      if (n < NN) out[(size_t)n * 64 + jt * 16 + n16] = acc[jt][r] - lse[r];
    }
}

// ---------------- launch ----------------

extern "C" void kernel_launch(void* const* d_in, const int* in_sizes, int n_in,
                              void* d_out, int out_size, void* d_ws, size_t ws_size,
                              hipStream_t stream) {
  const float* x = (const float*)d_in[0];
  const int* ei = (const int*)d_in[1];
  const float* Wl = (const float*)d_in[2];
  const float* bl = (const float*)d_in[3];
  const float* Wr = (const float*)d_in[4];
  const float* gmm = (const float*)d_in[5];
  const float* bta = (const float*)d_in[6];
  const float* Wf = (const float*)d_in[7];
  const float* bfp = (const float*)d_in[8];

  char* ws = (char*)d_ws;
  size_t off = 0;
  auto alloc = [&](size_t bytes) {
    void* p = ws + off;
    off = (off + bytes + 255) & ~(size_t)255;
    return p;
  };
  int* cnt = (int*)alloc((size_t)NN * 4);
  int* rp = (int*)alloc((size_t)(NN + 1) * 4);
  int* cursor = (int*)alloc((size_t)NN * 4);
  int* col = (int*)alloc((size_t)NE * 4);
  int* bsums = (int*)alloc((size_t)NB1 * 4);
  unsigned short* hb0 = (unsigned short*)alloc((size_t)NN * 128 * 2);
  unsigned short* hb1 = (unsigned short*)alloc((size_t)NN * 128 * 2);

  hipMemsetAsync(cnt, 0, (size_t)NN * 4, stream);
  k_count<<<(NE + 255) / 256, 256, 0, stream>>>(ei, cnt);
  k_scan1<<<NB1, 256, 0, stream>>>(cnt, rp, bsums);
  k_scan2<<<1, 128, 0, stream>>>(bsums);
  k_scan3<<<(NN + 255) / 256, 256, 0, stream>>>(rp, cursor, bsums);
  k_fill<<<(NE + 255) / 256, 256, 0, stream>>>(ei, cursor, col);
  k_cvt<<<(NN * 128 / 4 + 255) / 256, 256, 0, stream>>>(x, hb0);

  k_layer<<<NBT, 256, 0, stream>>>(hb0, hb1, rp, col, Wl, bl, Wr, gmm, bta);
  k_layer<<<NBT, 256, 0, stream>>>(hb1, hb0, rp, col, Wl + 16384, bl + 128, Wr + 16384,
                                   gmm + 128, bta + 128);
  k_layer<<<NBT, 256, 0, stream>>>(hb0, hb1, rp, col, Wl + 32768, bl + 256, Wr + 32768,
                                   gmm + 256, bta + 256);
  k_final<<<NBT, 256, 0, stream>>>(hb1, Wf, bfp, (float*)d_out);
}

// Round 2
// 463.922 us; speedup vs baseline: 1.9518x; 1.9518x over previous
//
#include <hip/hip_runtime.h>

#define NN 100000
#define NE 800000

static constexpr int NB1 = (NN + 1023) / 1024;  // scan pass-1 blocks = 98
static constexpr int NBT = (NN + 63) / 64;      // node-tile blocks = 1563

typedef __attribute__((ext_vector_type(8))) short short8;
typedef __attribute__((ext_vector_type(4))) float f32x4;

__device__ __forceinline__ unsigned short f2bf(float f) {
  unsigned int u = __float_as_uint(f);
  u += 0x7fffu + ((u >> 16) & 1u);
  return (unsigned short)(u >> 16);
}
__device__ __forceinline__ float bflo(unsigned int u) { return __uint_as_float(u << 16); }
__device__ __forceinline__ float bfhi(unsigned int u) { return __uint_as_float(u & 0xffff0000u); }

// ---------------- CSR build ----------------

__global__ void k_count(const int* __restrict__ ei, int* __restrict__ cnt) {
  int e = blockIdx.x * 256 + threadIdx.x;
  if (e < NE) atomicAdd(&cnt[ei[e]], 1);
}

__global__ void k_scan1(const int* __restrict__ cnt, int* __restrict__ rp,
                        int* __restrict__ bsums) {
  __shared__ int sm[256];
  const int b = blockIdx.x, t = threadIdx.x;
  const int base = b * 1024 + t * 4;
  int c0 = 0, c1 = 0, c2 = 0, c3 = 0;
  if (base + 4 <= NN) {
    int4 v = *(const int4*)(cnt + base);
    c0 = v.x; c1 = v.y; c2 = v.z; c3 = v.w;
  } else {
    if (base + 0 < NN) c0 = cnt[base + 0];
    if (base + 1 < NN) c1 = cnt[base + 1];
    if (base + 2 < NN) c2 = cnt[base + 2];
    if (base + 3 < NN) c3 = cnt[base + 3];
  }
  int tot = c0 + c1 + c2 + c3;
  sm[t] = tot;
  __syncthreads();
  for (int off = 1; off < 256; off <<= 1) {
    int v = (t >= off) ? sm[t - off] : 0;
    __syncthreads();
    sm[t] += v;
    __syncthreads();
  }
  int incl = sm[t];
  int excl = incl - tot;
  if (t == 255) bsums[b] = incl;
  int run = excl;
  if (base + 0 < NN) rp[base + 0] = run; run += c0;
  if (base + 1 < NN) rp[base + 1] = run; run += c1;
  if (base + 2 < NN) rp[base + 2] = run; run += c2;
  if (base + 3 < NN) rp[base + 3] = run;
}

__global__ void k_scan2(int* __restrict__ bsums) {
  __shared__ int sm[128];
  int t = threadIdx.x;
  int v = (t < NB1) ? bsums[t] : 0;
  sm[t] = v;
  __syncthreads();
  for (int off = 1; off < 128; off <<= 1) {
    int u = (t >= off) ? sm[t - off] : 0;
    __syncthreads();
    sm[t] += u;
    __syncthreads();
  }
  if (t < NB1) bsums[t] = sm[t] - v;  // exclusive
}

__global__ void k_scan3(int* __restrict__ rp, int* __restrict__ cursor,
                        const int* __restrict__ bsums) {
  int i = blockIdx.x * 256 + threadIdx.x;
  if (i < NN) {
    int v = rp[i] + bsums[i >> 10];
    rp[i] = v;
    cursor[i] = v;
  }
  if (i == 0) rp[NN] = NE;
}

__global__ void k_fill(const int* __restrict__ ei, int* __restrict__ cursor,
                       int* __restrict__ col) {
  int e = blockIdx.x * 256 + threadIdx.x;
  if (e < NE) {
    int d = ei[e];
    int pos = atomicAdd(&cursor[d], 1);
    col[pos] = ei[NE + e];
  }
}

// ---------------- x -> bf16 ----------------

__global__ void k_cvt(const float* __restrict__ x, unsigned short* __restrict__ hb) {
  int i = blockIdx.x * 256 + threadIdx.x;
  long long base = (long long)i * 4;
  if (base < (long long)NN * 128) {
    float4 v = *(const float4*)(x + base);
    unsigned long long pk = (unsigned long long)f2bf(v.x) |
                            ((unsigned long long)f2bf(v.y) << 16) |
                            ((unsigned long long)f2bf(v.z) << 32) |
                            ((unsigned long long)f2bf(v.w) << 48);
    *(unsigned long long*)(hb + base) = pk;
  }
}

// ---------------- W -> bf16 B-frag order (global, once) ----------------
// B-frag slot for 16x16x32: lane=q*16+j16 holds B[k=c*32+q*8+jj][j=jt*16+j16]
// index = (c*JT + jt)*512 + lane*8 + jj ; B[k][j] = W[j][k] (computing X @ W^T)

__global__ void k_prepW(const float* __restrict__ Wl, const float* __restrict__ Wr,
                        unsigned short* __restrict__ Wb) {
  int idx = blockIdx.x * 256 + threadIdx.x;  // 3 * 16384
  if (idx >= 3 * 16384) return;
  int layer = idx >> 14, r = idx & 16383;
  int j = r >> 7, k = r & 127;
  int c = k >> 5, q = (k >> 3) & 3, jj = k & 7, jt = j >> 4, j16 = j & 15;
  int slot = (c * 8 + jt) * 512 + (q * 16 + j16) * 8 + jj;
  Wb[layer * 32768 + slot] = f2bf(Wl[idx]);
  Wb[layer * 32768 + 16384 + slot] = f2bf(Wr[idx]);
}

__global__ void k_prepWf(const float* __restrict__ Wf, unsigned short* __restrict__ Wfb) {
  int idx = blockIdx.x * 256 + threadIdx.x;  // 8192
  if (idx >= 8192) return;
  int j = idx >> 7, k = idx & 127;
  int c = k >> 5, q = (k >> 3) & 3, jj = k & 7, jt = j >> 4, j16 = j & 15;
  Wfb[(c * 4 + jt) * 512 + (q * 16 + j16) * 8 + jj] = f2bf(Wf[idx]);
}

// ---------------- fused SAGE layer ----------------
// block = 256 (4 waves), 64 nodes/block (16/wave).
// LDS: agg rows only, row-major [64][136 shorts] = 17 KB -> 4+ blocks/CU.
// Gather: 2 nodes/wave concurrently (half-wave per node, 8B/lane), unroll-4.
// W read as B-frags straight from prepped global (L2-resident).
__global__ __launch_bounds__(256, 4)
void k_layer(const unsigned short* __restrict__ hin, unsigned short* __restrict__ hout,
             const int* __restrict__ rp, const int* __restrict__ col,
             const unsigned short* __restrict__ Wb, const float* __restrict__ bl,
             const float* __restrict__ gmm, const float* __restrict__ bta) {
  __shared__ unsigned short aggS[64 * 136];  // row stride 272B (17x16B): frag reads conflict-free
  const int t = threadIdx.x;
  const int w = t >> 6;
  const int lane = t & 63;
  const int nodeBase = blockIdx.x * 64;

  // prefetch own-row h A-frags (global, independent of gather)
  const int q = lane >> 4;
  const int n16 = lane & 15;
  int nrow = nodeBase + w * 16 + n16;
  const unsigned short* hrow = hin + (size_t)(nrow < NN ? nrow : NN - 1) * 128;
  short8 a_h[4];
#pragma unroll
  for (int c = 0; c < 4; ++c) a_h[c] = *(const short8*)(hrow + c * 32 + q * 8);

  // gather neighbor mean: half-wave per node, lane covers 4 features (8B)
  const unsigned long long* hin64 = (const unsigned long long*)hin;
  const int half = lane >> 5;
  const int jl = lane & 31;
  for (int mm = 0; mm < 8; ++mm) {
    int m = mm * 2 + half;
    int n = nodeBase + w * 16 + m;
    int e0 = 0, e1 = 0;
    if (n < NN) { e0 = rp[n]; e1 = rp[n + 1]; }
    float inv = 1.f / fmaxf((float)(e1 - e0), 1.f);
    float a0 = 0.f, a1 = 0.f, a2 = 0.f, a3 = 0.f;
    int e = e0;
    for (; e + 4 <= e1; e += 4) {
      int s0 = col[e], s1 = col[e + 1], s2 = col[e + 2], s3 = col[e + 3];
      unsigned long long u0 = hin64[(size_t)s0 * 32 + jl];
      unsigned long long u1 = hin64[(size_t)s1 * 32 + jl];
      unsigned long long u2 = hin64[(size_t)s2 * 32 + jl];
      unsigned long long u3 = hin64[(size_t)s3 * 32 + jl];
      unsigned int l0 = (unsigned int)u0, h0 = (unsigned int)(u0 >> 32);
      unsigned int l1 = (unsigned int)u1, h1 = (unsigned int)(u1 >> 32);
      unsigned int l2 = (unsigned int)u2, h2 = (unsigned int)(u2 >> 32);
      unsigned int l3 = (unsigned int)u3, h3 = (unsigned int)(u3 >> 32);
      a0 += bflo(l0) + bflo(l1) + bflo(l2) + bflo(l3);
      a1 += bfhi(l0) + bfhi(l1) + bfhi(l2) + bfhi(l3);
      a2 += bflo(h0) + bflo(h1) + bflo(h2) + bflo(h3);
      a3 += bfhi(h0) + bfhi(h1) + bfhi(h2) + bfhi(h3);
    }
    for (; e < e1; ++e) {
      unsigned long long u = hin64[(size_t)col[e] * 32 + jl];
      unsigned int lo = (unsigned int)u, hi = (unsigned int)(u >> 32);
      a0 += bflo(lo); a1 += bfhi(lo); a2 += bflo(hi); a3 += bfhi(hi);
    }
    a0 *= inv; a1 *= inv; a2 *= inv; a3 *= inv;
    unsigned long long pk = (unsigned long long)f2bf(a0) |
                            ((unsigned long long)f2bf(a1) << 16) |
                            ((unsigned long long)f2bf(a2) << 32) |
                            ((unsigned long long)f2bf(a3) << 48);
    *(unsigned long long*)&aggS[(w * 16 + m) * 136 + jl * 4] = pk;
  }
  __syncthreads();

  // MFMA: wave handles 16 nodes x 128 out; B-frags from global (L2)
  f32x4 acc[8];
#pragma unroll
  for (int jt = 0; jt < 8; ++jt) acc[jt] = (f32x4){0.f, 0.f, 0.f, 0.f};
  const unsigned short* aggrow = aggS + (w * 16 + n16) * 136;
#pragma unroll
  for (int c = 0; c < 4; ++c) {
    short8 a_agg = *(const short8*)(aggrow + c * 32 + q * 8);
#pragma unroll
    for (int jt = 0; jt < 8; ++jt) {
      short8 b_l = *(const short8*)(Wb + (c * 8 + jt) * 512 + lane * 8);
      short8 b_r = *(const short8*)(Wb + 16384 + (c * 8 + jt) * 512 + lane * 8);
      acc[jt] = __builtin_amdgcn_mfma_f32_16x16x32_bf16(a_agg, b_l, acc[jt], 0, 0, 0);
      acc[jt] = __builtin_amdgcn_mfma_f32_16x16x32_bf16(a_h[c], b_r, acc[jt], 0, 0, 0);
    }
  }

  // epilogue: +bias, LayerNorm over 128 feats (xor-shuffle in 16-lane groups), ReLU
  float blv[8], gv[8], bv[8];
#pragma unroll
  for (int jt = 0; jt < 8; ++jt) {
    int j = jt * 16 + n16;
    blv[jt] = bl[j];
    gv[jt] = gmm[j];
    bv[jt] = bta[j];
  }
  float s[4] = {0, 0, 0, 0}, ss[4] = {0, 0, 0, 0};
#pragma unroll
  for (int jt = 0; jt < 8; ++jt)
#pragma unroll
    for (int r = 0; r < 4; ++r) {
      float v = acc[jt][r] + blv[jt];
      acc[jt][r] = v;
      s[r] += v;
      ss[r] += v * v;
    }
#pragma unroll
  for (int mask = 1; mask < 16; mask <<= 1) {
#pragma unroll
    for (int r = 0; r < 4; ++r) {
      s[r] += __shfl_xor(s[r], mask, 64);
      ss[r] += __shfl_xor(ss[r], mask, 64);
    }
  }
  float mu[4], rs[4];
#pragma unroll
  for (int r = 0; r < 4; ++r) {
    mu[r] = s[r] * (1.f / 128.f);
    float var = ss[r] * (1.f / 128.f) - mu[r] * mu[r];
    rs[r] = rsqrtf(var + 1e-5f);
  }
#pragma unroll
  for (int jt = 0; jt < 8; ++jt)
#pragma unroll
    for (int r = 0; r < 4; ++r) {
      int n = nodeBase + w * 16 + q * 4 + r;
      if (n < NN) {
        float v = (acc[jt][r] - mu[r]) * rs[r] * gv[jt] + bv[jt];
        hout[(size_t)n * 128 + jt * 16 + n16] = f2bf(fmaxf(v, 0.f));
      }
    }
}

// ---------------- final linear + log_softmax ----------------
__global__ __launch_bounds__(256, 6)
void k_final(const unsigned short* __restrict__ hin, const unsigned short* __restrict__ Wfb,
             const float* __restrict__ bfp, float* __restrict__ out) {
  const int t = threadIdx.x;
  const int w = t >> 6;
  const int lane = t & 63;
  const int nodeBase = blockIdx.x * 64;

  f32x4 acc[4];
#pragma unroll
  for (int jt = 0; jt < 4; ++jt) acc[jt] = (f32x4){0.f, 0.f, 0.f, 0.f};
  const int q = lane >> 4;
  int nrow = nodeBase + w * 16 + (lane & 15);
  const unsigned short* hrow = hin + (size_t)(nrow < NN ? nrow : NN - 1) * 128;
#pragma unroll
  for (int c = 0; c < 4; ++c) {
    short8 a_h = *(const short8*)(hrow + c * 32 + q * 8);
#pragma unroll
    for (int jt = 0; jt < 4; ++jt) {
      short8 b = *(const short8*)(Wfb + (c * 4 + jt) * 512 + lane * 8);
      acc[jt] = __builtin_amdgcn_mfma_f32_16x16x32_bf16(a_h, b, acc[jt], 0, 0, 0);
    }
  }

  const int n16 = lane & 15;
  float bfv[4];
#pragma unroll
  for (int jt = 0; jt < 4; ++jt) bfv[jt] = bfp[jt * 16 + n16];
  float mx[4] = {-1e30f, -1e30f, -1e30f, -1e30f};
#pragma unroll
  for (int jt = 0; jt < 4; ++jt)
#pragma unroll
    for (int r = 0; r < 4; ++r) {
      float v = acc[jt][r] + bfv[jt];
      acc[jt][r] = v;
      mx[r] = fmaxf(mx[r], v);
    }
#pragma unroll
  for (int mask = 1; mask < 16; mask <<= 1)
#pragma unroll
    for (int r = 0; r < 4; ++r) mx[r] = fmaxf(mx[r], __shfl_xor(mx[r], mask, 64));
  float se[4] = {0, 0, 0, 0};
#pragma unroll
  for (int jt = 0; jt < 4; ++jt)
#pragma unroll
    for (int r = 0; r < 4; ++r) se[r] += expf(acc[jt][r] - mx[r]);
#pragma unroll
  for (int mask = 1; mask < 16; mask <<= 1)
#pragma unroll
    for (int r = 0; r < 4; ++r) se[r] += __shfl_xor(se[r], mask, 64);
  float lse[4];
#pragma unroll
  for (int r = 0; r < 4; ++r) lse[r] = mx[r] + logf(se[r]);
#pragma unroll
  for (int jt = 0; jt < 4; ++jt)
#pragma unroll
    for (int r = 0; r < 4; ++r) {
      int n = nodeBase + w * 16 + q * 4 + r;
      if (n < NN) out[(size_t)n * 64 + jt * 16 + n16] = acc[jt][r] - lse[r];
    }
}

// ---------------- launch ----------------

extern "C" void kernel_launch(void* const* d_in, const int* in_sizes, int n_in,
                              void* d_out, int out_size, void* d_ws, size_t ws_size,
                              hipStream_t stream) {
  const float* x = (const float*)d_in[0];
  const int* ei = (const int*)d_in[1];
  const float* Wl = (const float*)d_in[2];
  const float* bl = (const float*)d_in[3];
  const float* Wr = (const float*)d_in[4];
  const float* gmm = (const float*)d_in[5];
  const float* bta = (const float*)d_in[6];
  const float* Wf = (const float*)d_in[7];
  const float* bfp = (const float*)d_in[8];

  char* ws = (char*)d_ws;
  size_t off = 0;
  auto alloc = [&](size_t bytes) {
    void* p = ws + off;
    off = (off + bytes + 255) & ~(size_t)255;
    return p;
  };
  int* cnt = (int*)alloc((size_t)NN * 4);
  int* rp = (int*)alloc((size_t)(NN + 1) * 4);
  int* cursor = (int*)alloc((size_t)NN * 4);
  int* col = (int*)alloc((size_t)NE * 4);
  int* bsums = (int*)alloc((size_t)NB1 * 4);
  unsigned short* hb0 = (unsigned short*)alloc((size_t)NN * 128 * 2);
  unsigned short* hb1 = (unsigned short*)alloc((size_t)NN * 128 * 2);
  unsigned short* Wb = (unsigned short*)alloc((size_t)3 * 32768 * 2);
  unsigned short* Wfb = (unsigned short*)alloc((size_t)8192 * 2);

  hipMemsetAsync(cnt, 0, (size_t)NN * 4, stream);
  k_prepW<<<(3 * 16384 + 255) / 256, 256, 0, stream>>>(Wl, Wr, Wb);
  k_prepWf<<<(8192 + 255) / 256, 256, 0, stream>>>(Wf, Wfb);
  k_count<<<(NE + 255) / 256, 256, 0, stream>>>(ei, cnt);
  k_scan1<<<NB1, 256, 0, stream>>>(cnt, rp, bsums);
  k_scan2<<<1, 128, 0, stream>>>(bsums);
  k_scan3<<<(NN + 255) / 256, 256, 0, stream>>>(rp, cursor, bsums);
  k_fill<<<(NE + 255) / 256, 256, 0, stream>>>(ei, cursor, col);
  k_cvt<<<(NN * 128 / 4 + 255) / 256, 256, 0, stream>>>(x, hb0);

  k_layer<<<NBT, 256, 0, stream>>>(hb0, hb1, rp, col, Wb, bl, gmm, bta);
  k_layer<<<NBT, 256, 0, stream>>>(hb1, hb0, rp, col, Wb + 32768, bl + 128, gmm + 128,
                                   bta + 128);
  k_layer<<<NBT, 256, 0, stream>>>(hb0, hb1, rp, col, Wb + 65536, bl + 256, gmm + 256,
                                   bta + 256);
  k_final<<<NBT, 256, 0, stream>>>(hb1, Wfb, bfp, (float*)d_out);
}

// Round 3
// 393.124 us; speedup vs baseline: 2.3033x; 1.1801x over previous
//
#include <hip/hip_runtime.h>

#define NN 100000
#define NE 800000
#define CAP 1792  // LDS col-window capacity (block edge sum: mean 512, sigma 23)

static constexpr int NB1 = (NN + 1023) / 1024;  // scan pass-1 blocks = 98
static constexpr int NBT = (NN + 63) / 64;      // node-tile blocks = 1563

typedef __attribute__((ext_vector_type(8))) short short8;
typedef __attribute__((ext_vector_type(4))) float f32x4;
struct U2 { unsigned long long x, y; };

__device__ __forceinline__ unsigned short f2bf(float f) {
  unsigned int u = __float_as_uint(f);
  u += 0x7fffu + ((u >> 16) & 1u);
  return (unsigned short)(u >> 16);
}
__device__ __forceinline__ float bflo(unsigned int u) { return __uint_as_float(u << 16); }
__device__ __forceinline__ float bfhi(unsigned int u) { return __uint_as_float(u & 0xffff0000u); }

__device__ __forceinline__ void acc8(const U2& v, float* a) {
  unsigned int w0 = (unsigned int)v.x, w1 = (unsigned int)(v.x >> 32);
  unsigned int w2 = (unsigned int)v.y, w3 = (unsigned int)(v.y >> 32);
  a[0] += bflo(w0); a[1] += bfhi(w0); a[2] += bflo(w1); a[3] += bfhi(w1);
  a[4] += bflo(w2); a[5] += bfhi(w2); a[6] += bflo(w3); a[7] += bfhi(w3);
}

// ---------------- fused prep: x->bf16, degree count, W->bf16 B-frag ----------------
// B-frag slot for 16x16x32: lane=q*16+j16 holds B[k=c*32+q*8+jj][j=jt*16+j16]

__global__ void k_prep_all(const float* __restrict__ x, unsigned short* __restrict__ hb,
                           const int* __restrict__ ei, int* __restrict__ cnt,
                           const float* __restrict__ Wl, const float* __restrict__ Wr,
                           unsigned short* __restrict__ Wb, const float* __restrict__ Wf,
                           unsigned short* __restrict__ Wfb) {
  int i = blockIdx.x * 256 + threadIdx.x;
  long long base = (long long)i * 4;
  if (base < (long long)NN * 128) {
    float4 v = *(const float4*)(x + base);
    unsigned long long pk = (unsigned long long)f2bf(v.x) |
                            ((unsigned long long)f2bf(v.y) << 16) |
                            ((unsigned long long)f2bf(v.z) << 32) |
                            ((unsigned long long)f2bf(v.w) << 48);
    *(unsigned long long*)(hb + base) = pk;
  }
  if (i < NE) atomicAdd(&cnt[ei[i]], 1);
  if (i < 3 * 16384) {
    int layer = i >> 14, r = i & 16383;
    int j = r >> 7, k = r & 127;
    int c = k >> 5, q = (k >> 3) & 3, jj = k & 7, jt = j >> 4, j16 = j & 15;
    int slot = (c * 8 + jt) * 512 + (q * 16 + j16) * 8 + jj;
    Wb[layer * 32768 + slot] = f2bf(Wl[i]);
    Wb[layer * 32768 + 16384 + slot] = f2bf(Wr[i]);
  } else if (i < 3 * 16384 + 8192) {
    int idx = i - 3 * 16384;
    int j = idx >> 7, k = idx & 127;
    int c = k >> 5, q = (k >> 3) & 3, jj = k & 7, jt = j >> 4, j16 = j & 15;
    Wfb[(c * 4 + jt) * 512 + (q * 16 + j16) * 8 + jj] = f2bf(Wf[idx]);
  }
}

// ---------------- CSR scan + fill ----------------

__global__ void k_scan1(const int* __restrict__ cnt, int* __restrict__ rp,
                        int* __restrict__ bsums) {
  __shared__ int sm[256];
  const int b = blockIdx.x, t = threadIdx.x;
  const int base = b * 1024 + t * 4;
  int c0 = 0, c1 = 0, c2 = 0, c3 = 0;
  if (base + 4 <= NN) {
    int4 v = *(const int4*)(cnt + base);
    c0 = v.x; c1 = v.y; c2 = v.z; c3 = v.w;
  } else {
    if (base + 0 < NN) c0 = cnt[base + 0];
    if (base + 1 < NN) c1 = cnt[base + 1];
    if (base + 2 < NN) c2 = cnt[base + 2];
    if (base + 3 < NN) c3 = cnt[base + 3];
  }
  int tot = c0 + c1 + c2 + c3;
  sm[t] = tot;
  __syncthreads();
  for (int off = 1; off < 256; off <<= 1) {
    int v = (t >= off) ? sm[t - off] : 0;
    __syncthreads();
    sm[t] += v;
    __syncthreads();
  }
  int incl = sm[t];
  int excl = incl - tot;
  if (t == 255) bsums[b] = incl;
  int run = excl;
  if (base + 0 < NN) rp[base + 0] = run; run += c0;
  if (base + 1 < NN) rp[base + 1] = run; run += c1;
  if (base + 2 < NN) rp[base + 2] = run; run += c2;
  if (base + 3 < NN) rp[base + 3] = run;
}

__global__ void k_scan2(int* __restrict__ bsums) {
  __shared__ int sm[128];
  int t = threadIdx.x;
  int v = (t < NB1) ? bsums[t] : 0;
  sm[t] = v;
  __syncthreads();
  for (int off = 1; off < 128; off <<= 1) {
    int u = (t >= off) ? sm[t - off] : 0;
    __syncthreads();
    sm[t] += u;
    __syncthreads();
  }
  if (t < NB1) bsums[t] = sm[t] - v;  // exclusive
}

__global__ void k_scan3(int* __restrict__ rp, int* __restrict__ cursor,
                        const int* __restrict__ bsums) {
  int i = blockIdx.x * 256 + threadIdx.x;
  if (i < NN) {
    int v = rp[i] + bsums[i >> 10];
    rp[i] = v;
    cursor[i] = v;
  }
  if (i == 0) rp[NN] = NE;
}

__global__ void k_fill(const int* __restrict__ ei, int* __restrict__ cursor,
                       int* __restrict__ col) {
  int e = blockIdx.x * 256 + threadIdx.x;
  if (e < NE) {
    int d = ei[e];
    int pos = atomicAdd(&cursor[d], 1);
    col[pos] = ei[NE + e];
  }
}

// ---------------- fused SAGE layer ----------------
// block = 256 (4 waves), 64 nodes/block (16/wave).
// Gather: block's CSR edge window staged to LDS (contiguous!), then
// 4 nodes/wave concurrent (16 lanes each, 16B/lane), unroll-4 -> 4KB in flight/wave.
// LDS: colS 7KB + rpS 0.3KB + aggS 17KB (row stride 272B) ~ 25KB -> 6 blocks/CU.
__global__ __launch_bounds__(256, 6)
void k_layer(const unsigned short* __restrict__ hin, unsigned short* __restrict__ hout,
             const int* __restrict__ rp, const int* __restrict__ col,
             const unsigned short* __restrict__ Wb, const float* __restrict__ bl,
             const float* __restrict__ gmm, const float* __restrict__ bta) {
  __shared__ int colS[CAP];
  __shared__ int rpS[65];
  __shared__ unsigned short aggS[64 * 136];
  const int t = threadIdx.x;
  const int w = t >> 6;
  const int lane = t & 63;
  const int nodeBase = blockIdx.x * 64;

  // prefetch own-row h A-frags (independent of gather)
  const int q = lane >> 4;
  const int n16 = lane & 15;
  int nrow = nodeBase + w * 16 + n16;
  const unsigned short* hrow = hin + (size_t)(nrow < NN ? nrow : NN - 1) * 128;
  short8 a_h[4];
#pragma unroll
  for (int c = 0; c < 4; ++c) a_h[c] = *(const short8*)(hrow + c * 32 + q * 8);

  // stage edge window + row pointers
  const int rowEnd = (nodeBase + 64 <= NN) ? nodeBase + 64 : NN;
  const int eBase = rp[nodeBase];
  const int eEnd = rp[rowEnd];
  const int EB = eEnd - eBase;
  const bool inLds = (EB <= CAP);
  if (t < 65) {
    int r = nodeBase + t;
    rpS[t] = rp[r < NN ? r : NN];
  }
  if (inLds)
    for (int i = t; i < EB; i += 256) colS[i] = col[eBase + i];
  __syncthreads();

  // gather: group = 16 lanes per node, lane covers 8 features (16B)
  const int grp = lane >> 4;  // node within quartet
  const int jl = lane & 15;   // feature chunk
  auto rowAt = [&](int s) { return *(const U2*)(hin + (size_t)s * 128 + jl * 8); };
#pragma unroll
  for (int mm = 0; mm < 4; ++mm) {
    int li = w * 16 + mm * 4 + grp;
    int e0 = rpS[li], e1 = rpS[li + 1];
    float inv = 1.f / fmaxf((float)(e1 - e0), 1.f);
    float a[8] = {0.f, 0.f, 0.f, 0.f, 0.f, 0.f, 0.f, 0.f};
    if (inLds) {
      int le = e0 - eBase, lend = e1 - eBase;
      for (; le + 4 <= lend; le += 4) {
        int i0 = colS[le], i1 = colS[le + 1], i2 = colS[le + 2], i3 = colS[le + 3];
        U2 v0 = rowAt(i0), v1 = rowAt(i1), v2 = rowAt(i2), v3 = rowAt(i3);
        acc8(v0, a); acc8(v1, a); acc8(v2, a); acc8(v3, a);
      }
      for (; le < lend; ++le) { U2 v = rowAt(colS[le]); acc8(v, a); }
    } else {
      int e = e0;
      for (; e + 4 <= e1; e += 4) {
        int i0 = col[e], i1 = col[e + 1], i2 = col[e + 2], i3 = col[e + 3];
        U2 v0 = rowAt(i0), v1 = rowAt(i1), v2 = rowAt(i2), v3 = rowAt(i3);
        acc8(v0, a); acc8(v1, a); acc8(v2, a); acc8(v3, a);
      }
      for (; e < e1; ++e) { U2 v = rowAt(col[e]); acc8(v, a); }
    }
    unsigned int p0 = ((unsigned int)f2bf(a[1] * inv) << 16) | f2bf(a[0] * inv);
    unsigned int p1 = ((unsigned int)f2bf(a[3] * inv) << 16) | f2bf(a[2] * inv);
    unsigned int p2 = ((unsigned int)f2bf(a[5] * inv) << 16) | f2bf(a[4] * inv);
    unsigned int p3 = ((unsigned int)f2bf(a[7] * inv) << 16) | f2bf(a[6] * inv);
    *(uint4*)&aggS[li * 136 + jl * 8] = make_uint4(p0, p1, p2, p3);
  }
  __syncthreads();

  // MFMA: wave handles 16 nodes x 128 out; B-frags from prepped global (L2)
  f32x4 acc[8];
#pragma unroll
  for (int jt = 0; jt < 8; ++jt) acc[jt] = (f32x4){0.f, 0.f, 0.f, 0.f};
  const unsigned short* aggrow = aggS + (w * 16 + n16) * 136;
#pragma unroll
  for (int c = 0; c < 4; ++c) {
    short8 a_agg = *(const short8*)(aggrow + c * 32 + q * 8);
#pragma unroll
    for (int jt = 0; jt < 8; ++jt) {
      short8 b_l = *(const short8*)(Wb + (c * 8 + jt) * 512 + lane * 8);
      short8 b_r = *(const short8*)(Wb + 16384 + (c * 8 + jt) * 512 + lane * 8);
      acc[jt] = __builtin_amdgcn_mfma_f32_16x16x32_bf16(a_agg, b_l, acc[jt], 0, 0, 0);
      acc[jt] = __builtin_amdgcn_mfma_f32_16x16x32_bf16(a_h[c], b_r, acc[jt], 0, 0, 0);
    }
  }

  // epilogue: +bias, LayerNorm (xor-shuffle over 16-lane groups), ReLU
  float blv[8], gv[8], bv[8];
#pragma unroll
  for (int jt = 0; jt < 8; ++jt) {
    int j = jt * 16 + n16;
    blv[jt] = bl[j];
    gv[jt] = gmm[j];
    bv[jt] = bta[j];
  }
  float s[4] = {0, 0, 0, 0}, ss[4] = {0, 0, 0, 0};
#pragma unroll
  for (int jt = 0; jt < 8; ++jt)
#pragma unroll
    for (int r = 0; r < 4; ++r) {
      float v = acc[jt][r] + blv[jt];
      acc[jt][r] = v;
      s[r] += v;
      ss[r] += v * v;
    }
#pragma unroll
  for (int mask = 1; mask < 16; mask <<= 1) {
#pragma unroll
    for (int r = 0; r < 4; ++r) {
      s[r] += __shfl_xor(s[r], mask, 64);
      ss[r] += __shfl_xor(ss[r], mask, 64);
    }
  }
  float mu[4], rs[4];
#pragma unroll
  for (int r = 0; r < 4; ++r) {
    mu[r] = s[r] * (1.f / 128.f);
    float var = ss[r] * (1.f / 128.f) - mu[r] * mu[r];
    rs[r] = rsqrtf(var + 1e-5f);
  }
#pragma unroll
  for (int jt = 0; jt < 8; ++jt)
#pragma unroll
    for (int r = 0; r < 4; ++r) {
      int n = nodeBase + w * 16 + q * 4 + r;
      if (n < NN) {
        float v = (acc[jt][r] - mu[r]) * rs[r] * gv[jt] + bv[jt];
        hout[(size_t)n * 128 + jt * 16 + n16] = f2bf(fmaxf(v, 0.f));
      }
    }
}

// ---------------- final linear + log_softmax ----------------
__global__ __launch_bounds__(256, 8)
void k_final(const unsigned short* __restrict__ hin, const unsigned short* __restrict__ Wfb,
             const float* __restrict__ bfp, float* __restrict__ out) {
  const int t = threadIdx.x;
  const int w = t >> 6;
  const int lane = t & 63;
  const int nodeBase = blockIdx.x * 64;

  f32x4 acc[4];
#pragma unroll
  for (int jt = 0; jt < 4; ++jt) acc[jt] = (f32x4){0.f, 0.f, 0.f, 0.f};
  const int q = lane >> 4;
  int nrow = nodeBase + w * 16 + (lane & 15);
  const unsigned short* hrow = hin + (size_t)(nrow < NN ? nrow : NN - 1) * 128;
#pragma unroll
  for (int c = 0; c < 4; ++c) {
    short8 a_h = *(const short8*)(hrow + c * 32 + q * 8);
#pragma unroll
    for (int jt = 0; jt < 4; ++jt) {
      short8 b = *(const short8*)(Wfb + (c * 4 + jt) * 512 + lane * 8);
      acc[jt] = __builtin_amdgcn_mfma_f32_16x16x32_bf16(a_h, b, acc[jt], 0, 0, 0);
    }
  }

  const int n16 = lane & 15;
  float bfv[4];
#pragma unroll
  for (int jt = 0; jt < 4; ++jt) bfv[jt] = bfp[jt * 16 + n16];
  float mx[4] = {-1e30f, -1e30f, -1e30f, -1e30f};
#pragma unroll
  for (int jt = 0; jt < 4; ++jt)
#pragma unroll
    for (int r = 0; r < 4; ++r) {
      float v = acc[jt][r] + bfv[jt];
      acc[jt][r] = v;
      mx[r] = fmaxf(mx[r], v);
    }
#pragma unroll
  for (int mask = 1; mask < 16; mask <<= 1)
#pragma unroll
    for (int r = 0; r < 4; ++r) mx[r] = fmaxf(mx[r], __shfl_xor(mx[r], mask, 64));
  float se[4] = {0, 0, 0, 0};
#pragma unroll
  for (int jt = 0; jt < 4; ++jt)
#pragma unroll
    for (int r = 0; r < 4; ++r) se[r] += expf(acc[jt][r] - mx[r]);
#pragma unroll
  for (int mask = 1; mask < 16; mask <<= 1)
#pragma unroll
    for (int r = 0; r < 4; ++r) se[r] += __shfl_xor(se[r], mask, 64);
  float lse[4];
#pragma unroll
  for (int r = 0; r < 4; ++r) lse[r] = mx[r] + logf(se[r]);
#pragma unroll
  for (int jt = 0; jt < 4; ++jt)
#pragma unroll
    for (int r = 0; r < 4; ++r) {
      int n = nodeBase + w * 16 + q * 4 + r;
      if (n < NN) out[(size_t)n * 64 + jt * 16 + n16] = acc[jt][r] - lse[r];
    }
}

// ---------------- launch ----------------

extern "C" void kernel_launch(void* const* d_in, const int* in_sizes, int n_in,
                              void* d_out, int out_size, void* d_ws, size_t ws_size,
                              hipStream_t stream) {
  const float* x = (const float*)d_in[0];
  const int* ei = (const int*)d_in[1];
  const float* Wl = (const float*)d_in[2];
  const float* bl = (const float*)d_in[3];
  const float* Wr = (const float*)d_in[4];
  const float* gmm = (const float*)d_in[5];
  const float* bta = (const float*)d_in[6];
  const float* Wf = (const float*)d_in[7];
  const float* bfp = (const float*)d_in[8];

  char* ws = (char*)d_ws;
  size_t off = 0;
  auto alloc = [&](size_t bytes) {
    void* p = ws + off;
    off = (off + bytes + 255) & ~(size_t)255;
    return p;
  };
  int* cnt = (int*)alloc((size_t)NN * 4);
  int* rp = (int*)alloc((size_t)(NN + 1) * 4);
  int* cursor = (int*)alloc((size_t)NN * 4);
  int* col = (int*)alloc((size_t)NE * 4);
  int* bsums = (int*)alloc((size_t)NB1 * 4);
  unsigned short* hb0 = (unsigned short*)alloc((size_t)NN * 128 * 2);
  unsigned short* hb1 = (unsigned short*)alloc((size_t)NN * 128 * 2);
  unsigned short* Wb = (unsigned short*)alloc((size_t)3 * 32768 * 2);
  unsigned short* Wfb = (unsigned short*)alloc((size_t)8192 * 2);

  hipMemsetAsync(cnt, 0, (size_t)NN * 4, stream);
  k_prep_all<<<(NN * 128 / 4 + 255) / 256, 256, 0, stream>>>(x, hb0, ei, cnt, Wl, Wr, Wb,
                                                             Wf, Wfb);
  k_scan1<<<NB1, 256, 0, stream>>>(cnt, rp, bsums);
  k_scan2<<<1, 128, 0, stream>>>(bsums);
  k_scan3<<<(NN + 255) / 256, 256, 0, stream>>>(rp, cursor, bsums);
  k_fill<<<(NE + 255) / 256, 256, 0, stream>>>(ei, cursor, col);

  k_layer<<<NBT, 256, 0, stream>>>(hb0, hb1, rp, col, Wb, bl, gmm, bta);
  k_layer<<<NBT, 256, 0, stream>>>(hb1, hb0, rp, col, Wb + 32768, bl + 128, gmm + 128,
                                   bta + 128);
  k_layer<<<NBT, 256, 0, stream>>>(hb0, hb1, rp, col, Wb + 65536, bl + 256, gmm + 256,
                                   bta + 256);
  k_final<<<NBT, 256, 0, stream>>>(hb1, Wfb, bfp, (float*)d_out);
}